// Round 4
// 1929.802 us; speedup vs baseline: 1.0303x; 1.0303x over previous
//
#include <hip/hip_runtime.h>

#define EMB 768
#define NB 128
#define MB 1024
#define XROWS 2306  // 3*EMB+2

typedef __attribute__((ext_vector_type(8))) short short8;   // bf16x8 MFMA frag
typedef __attribute__((ext_vector_type(4))) float f32x4;

__device__ __forceinline__ unsigned short f2bf_bits(float f) {
    union { float f; unsigned u; } v; v.f = f;
    unsigned r = v.u + 0x7fffu + ((v.u >> 16) & 1u);  // RNE
    return (unsigned short)(r >> 16);
}
__device__ __forceinline__ unsigned pk2(float a, float b) {
    return (unsigned)f2bf_bits(a) | ((unsigned)f2bf_bits(b) << 16);
}
__device__ __forceinline__ float tanh_fast(float x) {
    float e = __expf(2.0f * x);
    return 1.0f - 2.0f / (e + 1.0f);   // saturates correctly at +-1
}
__device__ __forceinline__ short8 cvt_bf16x8(f32x4 x0, f32x4 x1) {
    short8 r;
    r[0] = (short)f2bf_bits(x0[0]); r[1] = (short)f2bf_bits(x0[1]);
    r[2] = (short)f2bf_bits(x0[2]); r[3] = (short)f2bf_bits(x0[3]);
    r[4] = (short)f2bf_bits(x1[0]); r[5] = (short)f2bf_bits(x1[1]);
    r[6] = (short)f2bf_bits(x1[2]); r[7] = (short)f2bf_bits(x1[3]);
    return r;
}

// ---------------- kernel 0: Wa fp32 -> bf16 (same [k][e] layout) ----------------
__global__ __launch_bounds__(256) void cvt_wa(const float* __restrict__ Wa,
                                              unsigned short* __restrict__ waB) {
    int i = (blockIdx.x * 256 + threadIdx.x) * 4;   // 192 blocks * 256 * 4 = 196608
    f32x4 v = *(const f32x4*)(Wa + i);
    uint2 u; u.x = pk2(v[0], v[1]); u.y = pk2(v[2], v[3]);
    *(uint2*)(waB + i) = u;
}

// ---------------- kernel 1: fused attention scores + softmax + pooling ----------------
// block = 1 sample, 512 threads (8 waves). Computes U^T[n,k] for Q/P1/P2 via MFMA,
// then score/softmax (beta kept in LDS), then beta-weighted pooling in-block while
// the sample's X slice is still L3-resident. qv extraction is fused into staging.
__global__ __launch_bounds__(512) void attn_pool(const float* __restrict__ X,
                                                 const unsigned short* __restrict__ waB,
                                                 const float* __restrict__ va,
                                                 float* __restrict__ Xin) {
    const int m = blockIdx.x;
    const int t = threadIdx.x;
    const int lane = t & 63;
    const int w = t >> 6;
    const int wnt = w & 3;       // n-tile pair
    const int wkt = w >> 2;      // k-tile half
    const int rq = lane & 15;
    const int quad = lane >> 4;
    const float* Xm = X + (size_t)m * XROWS * NB;

    __shared__ __attribute__((aligned(16))) unsigned short lX[3][128][40];
    __shared__ float sS1[2][128];
    __shared__ float sS2[2][128];
    __shared__ __attribute__((aligned(16))) float sBeta[2][128];

    f32x4 accQ[2][4], acc1[2][4], acc2[2][4];
    f32x4 z4 = {0.f, 0.f, 0.f, 0.f};
#pragma unroll
    for (int i = 0; i < 2; ++i)
#pragma unroll
        for (int c = 0; c < 4; ++c) { accQ[i][c] = z4; acc1[i][c] = z4; acc2[i][c] = z4; }

    const int tn = t & 127;      // n for staging
    const int th = t >> 7;       // 0..3: e'-chunk of 8
    const int rowbase[3] = {0, EMB, 2 * EMB + 1};
    float* qout = Xin + (size_t)(2 * MB + m) * EMB;   // qv destination

    for (int e0 = 0; e0 < EMB; e0 += 32) {
        __syncthreads();
#pragma unroll
        for (int mat = 0; mat < 3; ++mat) {
            const float* src = Xm + (size_t)(rowbase[mat] + e0 + th * 8) * NB + tn;
            float v0 = src[0 * NB], v1 = src[1 * NB], v2 = src[2 * NB], v3 = src[3 * NB];
            float v4 = src[4 * NB], v5 = src[5 * NB], v6 = src[6 * NB], v7 = src[7 * NB];
            if (mat == 0 && tn == 0) {
                // these are exactly Xq[e0+th*8 .. +7][0] = qv slice: write it now, free
                f32x4 q0 = {v0, v1, v2, v3};
                f32x4 q1 = {v4, v5, v6, v7};
                *(f32x4*)(qout + e0 + th * 8)     = q0;
                *(f32x4*)(qout + e0 + th * 8 + 4) = q1;
            }
            uint4 u;
            u.x = pk2(v0, v1); u.y = pk2(v2, v3); u.z = pk2(v4, v5); u.w = pk2(v6, v7);
            *(uint4*)&lX[mat][tn][th * 8] = u;
        }
        __syncthreads();

        short8 aq[2], a1[2], a2[2];
#pragma unroll
        for (int i = 0; i < 2; ++i) {
            int n = (2 * wnt + i) * 16 + rq;
            aq[i] = *(const short8*)&lX[0][n][quad * 8];
            a1[i] = *(const short8*)&lX[1][n][quad * 8];
            a2[i] = *(const short8*)&lX[2][n][quad * 8];
        }
#pragma unroll
        for (int c = 0; c < 4; ++c) {
            int kt = wkt * 4 + c;
            const unsigned short* wr = waB + (size_t)(kt * 16 + rq) * (2 * EMB) + e0 + quad * 8;
            short8 bq = *(const short8*)wr;
            short8 bp = *(const short8*)(wr + EMB);
#pragma unroll
            for (int i = 0; i < 2; ++i) {
                accQ[i][c] = __builtin_amdgcn_mfma_f32_16x16x32_bf16(aq[i], bq, accQ[i][c], 0, 0, 0);
                acc1[i][c] = __builtin_amdgcn_mfma_f32_16x16x32_bf16(a1[i], bp, acc1[i][c], 0, 0, 0);
                acc2[i][c] = __builtin_amdgcn_mfma_f32_16x16x32_bf16(a2[i], bp, acc2[i][c], 0, 0, 0);
            }
        }
    }

    // epilogue: s[n] = sum_k va[k] * tanh(Uq + Up)
    float vaf[4];
#pragma unroll
    for (int c = 0; c < 4; ++c) vaf[c] = va[(wkt * 4 + c) * 16 + rq];

    float s1p[2][4], s2p[2][4];
#pragma unroll
    for (int i = 0; i < 2; ++i)
#pragma unroll
        for (int r = 0; r < 4; ++r) { s1p[i][r] = 0.f; s2p[i][r] = 0.f; }

#pragma unroll
    for (int i = 0; i < 2; ++i)
#pragma unroll
        for (int c = 0; c < 4; ++c)
#pragma unroll
            for (int r = 0; r < 4; ++r) {
                float uq = accQ[i][c][r];
                s1p[i][r] += vaf[c] * tanh_fast(uq + acc1[i][c][r]);
                s2p[i][r] += vaf[c] * tanh_fast(uq + acc2[i][c][r]);
            }
#pragma unroll
    for (int mask = 1; mask < 16; mask <<= 1)
#pragma unroll
        for (int i = 0; i < 2; ++i)
#pragma unroll
            for (int r = 0; r < 4; ++r) {
                s1p[i][r] += __shfl_xor(s1p[i][r], mask, 64);
                s2p[i][r] += __shfl_xor(s2p[i][r], mask, 64);
            }
    if (rq == 0) {
#pragma unroll
        for (int i = 0; i < 2; ++i)
#pragma unroll
            for (int r = 0; r < 4; ++r) {
                int n = (2 * wnt + i) * 16 + quad * 4 + r;
                sS1[wkt][n] = s1p[i][r];
                sS2[wkt][n] = s2p[i][r];
            }
    }
    __syncthreads();

    if (w < 2) {  // wave 0 -> beta1, wave 1 -> beta2  (into LDS, no global round-trip)
        const float* sA = (w == 0) ? sS1[0] : sS2[0];
        const float* sB = (w == 0) ? sS1[1] : sS2[1];
        const int vrow = (w == 0) ? (2 * EMB) : (3 * EMB + 1);
        int n0 = 2 * lane, n1 = n0 + 1;
        float a = (sA[n0] + sB[n0]) * Xm[(size_t)vrow * NB + n0];
        float b = (sA[n1] + sB[n1]) * Xm[(size_t)vrow * NB + n1];
        float mx = fmaxf(a, b);
#pragma unroll
        for (int mask = 1; mask < 64; mask <<= 1) mx = fmaxf(mx, __shfl_xor(mx, mask, 64));
        float ea = __expf(a - mx), eb = __expf(b - mx);
        float sm = ea + eb;
#pragma unroll
        for (int mask = 1; mask < 64; mask <<= 1) sm += __shfl_xor(sm, mask, 64);
        float inv = 1.0f / sm;
        sBeta[w][n0] = ea * inv;
        sBeta[w][n1] = eb * inv;
    }
    __syncthreads();

    // pooling: p[e] = sum_n beta[n] * Xp[e][n]; X slice is L3-hot (just streamed).
    // 32 lanes per row (4 floats/lane), two rows per wave-iter (half = lane>>5).
    {
        const int l32 = lane & 31;
        const int half = lane >> 5;
        f32x4 b1v = *(const f32x4*)&sBeta[0][l32 * 4];
        f32x4 b2v = *(const f32x4*)&sBeta[1][l32 * 4];
        const float* Xp1 = Xm + (size_t)EMB * NB;
        const float* Xp2 = Xm + (size_t)(2 * EMB + 1) * NB;
        float* o1 = Xin + (size_t)m * EMB;
        float* o2 = Xin + (size_t)(MB + m) * EMB;
#pragma unroll 2
        for (int i = 0; i < 48; ++i) {
            int e = (i * 8 + w) * 2 + half;
            f32x4 x1 = *(const f32x4*)(Xp1 + (size_t)e * NB + l32 * 4);
            f32x4 x2 = *(const f32x4*)(Xp2 + (size_t)e * NB + l32 * 4);
            float p1 = x1[0] * b1v[0] + x1[1] * b1v[1] + x1[2] * b1v[2] + x1[3] * b1v[3];
            float p2 = x2[0] * b2v[0] + x2[1] * b2v[1] + x2[2] * b2v[2] + x2[3] * b2v[3];
#pragma unroll
            for (int mask = 1; mask < 32; mask <<= 1) {
                p1 += __shfl_xor(p1, mask, 64);
                p2 += __shfl_xor(p2, mask, 64);
            }
            if (l32 == 0) {
                o1[e] = p1;
                o2[e] = p2;
            }
        }
    }
}

// ---------------- kernel 3/4: Y = act(A @ W^T + b), A:(3072,768) W:(768,768) ----------------
__global__ __launch_bounds__(256) void mlp_gemm(const float* __restrict__ A,
                                                const float* __restrict__ W,
                                                const float* __restrict__ bias,
                                                float* __restrict__ Y, int doRelu) {
    const int bm = blockIdx.x;   // 24 x 128 rows
    const int bn = blockIdx.y;   // 6 x 128 cols
    const int t = threadIdx.x;
    const int lane = t & 63;
    const int w = t >> 6;
    const int rq = lane & 15, quad = lane >> 4;
    f32x4 acc[2][8];
    f32x4 z4 = {0.f, 0.f, 0.f, 0.f};
#pragma unroll
    for (int i = 0; i < 2; ++i)
#pragma unroll
        for (int nt = 0; nt < 8; ++nt) acc[i][nt] = z4;

    for (int e0 = 0; e0 < EMB; e0 += 32) {
        short8 af[2];
#pragma unroll
        for (int i = 0; i < 2; ++i) {
            const float* p = A + (size_t)(bm * 128 + (w * 2 + i) * 16 + rq) * EMB + e0 + quad * 8;
            af[i] = cvt_bf16x8(*(const f32x4*)p, *(const f32x4*)(p + 4));
        }
#pragma unroll
        for (int nt = 0; nt < 8; ++nt) {
            const float* p = W + (size_t)(bn * 128 + nt * 16 + rq) * EMB + e0 + quad * 8;
            short8 bf = cvt_bf16x8(*(const f32x4*)p, *(const f32x4*)(p + 4));
#pragma unroll
            for (int i = 0; i < 2; ++i)
                acc[i][nt] = __builtin_amdgcn_mfma_f32_16x16x32_bf16(af[i], bf, acc[i][nt], 0, 0, 0);
        }
    }
#pragma unroll
    for (int i = 0; i < 2; ++i)
#pragma unroll
        for (int nt = 0; nt < 8; ++nt) {
            int f = bn * 128 + nt * 16 + rq;
            float bv = bias[f];
#pragma unroll
            for (int r = 0; r < 4; ++r) {
                int row = bm * 128 + (w * 2 + i) * 16 + quad * 4 + r;
                float v = acc[i][nt][r] + bv;
                if (doRelu) v = fmaxf(v, 0.0f);
                Y[(size_t)row * EMB + f] = v;
            }
        }
}

// ---------------- kernel 5: head ----------------
__global__ __launch_bounds__(256) void head_kernel(const float* __restrict__ Z,
                                                   const float* __restrict__ W3,
                                                   const float* __restrict__ b3,
                                                   float* __restrict__ out) {
    const int m = blockIdx.x;
    const int t = threadIdx.x;
    float p = 0.0f;
    for (int e = t; e < EMB; e += 256) {
        float z1 = Z[(size_t)m * EMB + e];
        float z2 = Z[(size_t)(MB + m) * EMB + e];
        float zq = Z[(size_t)(2 * MB + m) * EMB + e];
        p += W3[e] * z1 + W3[EMB + e] * z2 + W3[2 * EMB + e] * fabsf(z1 - z2)
           + W3[3 * EMB + e] * fabsf(z1 - zq) + W3[4 * EMB + e] * fabsf(z2 - zq);
    }
#pragma unroll
    for (int mask = 1; mask < 64; mask <<= 1) p += __shfl_xor(p, mask, 64);
    __shared__ float sp[4];
    if ((t & 63) == 0) sp[t >> 6] = p;
    __syncthreads();
    if (t == 0) out[m] = fmaxf(sp[0] + sp[1] + sp[2] + sp[3] + b3[0], 0.0f);
}

// ---------------- launch ----------------
extern "C" void kernel_launch(void* const* d_in, const int* in_sizes, int n_in,
                              void* d_out, int out_size, void* d_ws, size_t ws_size,
                              hipStream_t stream) {
    const float* X  = (const float*)d_in[0];
    const float* Wa = (const float*)d_in[1];
    const float* va = (const float*)d_in[2];
    const float* W1 = (const float*)d_in[3];
    const float* b1 = (const float*)d_in[4];
    const float* W2 = (const float*)d_in[5];
    const float* b2 = (const float*)d_in[6];
    const float* W3 = (const float*)d_in[7];
    const float* b3 = (const float*)d_in[8];
    float* out = (float*)d_out;

    char* wsb = (char*)d_ws;
    // ws layout (bytes): waB 393216 | Xin 9.0 MB | Y1 9.0 MB | Z 9.0 MB  (~27.4 MB total)
    unsigned short* waB = (unsigned short*)wsb;
    float* Xin  = (float*)(wsb + 393216);
    float* Y1   = (float*)(wsb + 9830400);
    float* Z    = (float*)(wsb + 19267584);

    cvt_wa<<<192, 256, 0, stream>>>(Wa, waB);
    attn_pool<<<MB, 512, 0, stream>>>(X, waB, va, Xin);
    mlp_gemm<<<dim3(24, 6), 256, 0, stream>>>(Xin, W1, b1, Y1, 0);
    mlp_gemm<<<dim3(24, 6), 256, 0, stream>>>(Y1, W2, b2, Z, 1);
    head_kernel<<<MB, 256, 0, stream>>>(Z, W3, b3, out);
}